// Round 14
// baseline (104.729 us; speedup 1.0000x reference)
//
#include <hip/hip_runtime.h>
#include <hip/hip_bf16.h>

#define NTOK 2048
#define BATCH 4
#define EMB 256
#define NH 8
#define DHD 32
#define MROWS (NTOK*BATCH)      // 8192
#define NBE (MROWS*EMB)         // 2097152

typedef __attribute__((ext_vector_type(8))) __bf16 bf16x8;
typedef __attribute__((ext_vector_type(4))) float f32x4;
typedef __attribute__((ext_vector_type(8))) unsigned short ushort8;
typedef __attribute__((ext_vector_type(4))) unsigned int uint4v;

__device__ __forceinline__ unsigned short f2bf(float f){
  unsigned int u = __builtin_bit_cast(unsigned int, f);
  u += 0x7fffu + ((u >> 16) & 1u);
  return (unsigned short)(u >> 16);
}
__device__ __forceinline__ float fexp2(float x){
#if __has_builtin(__builtin_amdgcn_exp2f)
  return __builtin_amdgcn_exp2f(x);
#else
  return exp2f(x);
#endif
}

// fold 1/sqrt(32) * log2(e) into q so scores are in log2 domain
#define QSC (0.17677669529663687f * 1.4426950408889634f)

// ---------------- K1: qin = bf16(x + query_pos) ----------------
__global__ __launch_bounds__(256) void k_add(const float* __restrict__ x,
                                             const float* __restrict__ qp,
                                             unsigned short* __restrict__ qin){
  int i = blockIdx.x * 256 + threadIdx.x;
  f32x4 a0 = ((const f32x4*)x)[2*i];
  f32x4 a1 = ((const f32x4*)x)[2*i+1];
  f32x4 b0 = ((const f32x4*)qp)[2*i];
  f32x4 b1 = ((const f32x4*)qp)[2*i+1];
  ushort8 o;
#pragma unroll
  for (int j = 0; j < 4; ++j){
    o[j]   = f2bf(a0[j] + b0[j]);
    o[j+4] = f2bf(a1[j] + b1[j]);
  }
  ((ushort8*)qin)[i] = o;
}

// ---------------- K2: tiled transpose+cast of 5 weights: wt[n][k] = bf16(W[k][n]) ----------------
__global__ __launch_bounds__(256) void k_transW(const float* __restrict__ s0,
                                                const float* __restrict__ s1,
                                                const float* __restrict__ s2,
                                                const float* __restrict__ s3,
                                                const float* __restrict__ s4,
                                                unsigned short* __restrict__ wt){
  const float* srcs[5] = {s0, s1, s2, s3, s4};
  __shared__ float lds[64][65];
  int wi = blockIdx.z;
  int k0 = blockIdx.x * 64;
  int n0 = blockIdx.y * 64;
  int tid = threadIdx.x;
  const float* src = srcs[wi];
#pragma unroll
  for (int p = 0; p < 4; ++p){
    int r = p*16 + (tid>>4);
    int c = (tid&15)*4;
    f32x4 v = *(const f32x4*)(src + (k0+r)*256 + n0 + c);
#pragma unroll
    for (int j = 0; j < 4; ++j) lds[r][c+j] = v[j];
  }
  __syncthreads();
#pragma unroll
  for (int p = 0; p < 4; ++p){
    int nr = p*16 + (tid>>4);
    int kc = (tid&15)*4;
    unsigned long long pk = 0;
#pragma unroll
    for (int j = 0; j < 4; ++j)
      pk |= ((unsigned long long)f2bf(lds[kc+j][nr])) << (16*j);
    *(unsigned long long*)(wt + wi*65536 + (n0+nr)*256 + k0 + kc) = pk;
  }
}

// ---------------- K3: fused 4-way projection GEMM ----------------
// q/k epilogues: per-wave LDS staging (no barrier), 32B/lane stores.
// vr/vs epilogues: block LDS f32 staging + barrier + fully vectorized
// f32x4 read-modify-write against recv/send (was scalar 4B: the r13 bottleneck).
__global__ __launch_bounds__(256) void k_proj(const unsigned short* __restrict__ qin,
                                              const unsigned short* __restrict__ wt,
                                              const float* __restrict__ bq,
                                              const float* __restrict__ bk,
                                              const float* __restrict__ br,
                                              const float* __restrict__ bs,
                                              const float* __restrict__ recv,
                                              const float* __restrict__ send,
                                              unsigned short* __restrict__ qbuf,
                                              unsigned short* __restrict__ kpk,
                                              float* __restrict__ vrout,
                                              float* __restrict__ vsout){
  int m0 = blockIdx.x * 64;
  int gc = blockIdx.y * 64;
  int widx = gc >> 8;
  int c0 = gc & 255;
  int tid = threadIdx.x;
  int w = tid >> 6, lane = tid & 63;
  int lr = lane & 15, lg = lane >> 4;

  __shared__ __align__(16) float shmemF[64*68];   // aliased: bf16 st view or f32 tile

  const unsigned short* wtp = wt + widx * 65536;
  const unsigned short* aptr = qin + (m0 + w*16 + lr) * 256 + lg * 8;

  f32x4 acc[4];
#pragma unroll
  for (int f = 0; f < 4; ++f) acc[f] = (f32x4){0.f, 0.f, 0.f, 0.f};

#pragma unroll
  for (int k0 = 0; k0 < 256; k0 += 32){
    bf16x8 af = *(const bf16x8*)(aptr + k0);
#pragma unroll
    for (int f = 0; f < 4; ++f){
      bf16x8 bfrag = *(const bf16x8*)(wtp + (c0 + f*16 + lr) * 256 + k0 + lg * 8);
      acc[f] = __builtin_amdgcn_mfma_f32_16x16x32_bf16(af, bfrag, acc[f], 0, 0, 0);
    }
  }

  const float* bias = (widx == 0) ? bq : (widx == 1) ? bk : (widx == 2) ? br : bs;

  if (widx <= 1){
    unsigned short (*st)[16][72] = (unsigned short(*)[16][72])shmemF;
    // stage bf16 tile to this wave's LDS slab (same-wave produce/consume, no barrier)
#pragma unroll
    for (int f = 0; f < 4; ++f){
#pragma unroll
      for (int i = 0; i < 4; ++i){
        int c = c0 + f*16 + lr;
        float v = acc[f][i] + bias[c];
        st[w][lg*4+i][f*16+lr] = f2bf(widx == 0 ? v * QSC : v);
      }
    }
    if (widx == 0){
      int r = lane >> 2, co = (lane & 3) * 16;
      ushort8 a0 = *(ushort8*)&st[w][r][co];
      ushort8 a1 = *(ushort8*)&st[w][r][co + 8];
      unsigned short* dst = qbuf + (m0 + w*16 + r) * 256 + c0 + co;
      *(ushort8*)dst = a0;
      *(ushort8*)(dst + 8) = a1;
    } else {
      int cid = lane >> 3, s = lane & 7;
      int bb = cid >> 1, hr = cid & 1;
      int toko = s >> 1, dp = (s & 1) * 16;
      ushort8 a0 = *(ushort8*)&st[w][toko*4 + bb][hr*32 + dp];
      ushort8 a1 = *(ushort8*)&st[w][toko*4 + bb][hr*32 + dp + 8];
      int h  = (c0 >> 5) + hr;
      int n0 = (m0 + w*16) >> 2;          // first token of this wave's tile (mult of 4)
      int t0 = n0 & 63;
      int p0 = (((t0>>5)&1)<<4) + (((t0>>2)&1)<<5) + (((t0>>3)&3)<<2);
      unsigned short* dst = kpk + (bb*8 + h)*65536 + ((n0 & ~63) + p0 + toko)*32 + dp;
      *(ushort8*)dst = a0;
      *(ushort8*)(dst + 8) = a1;
    }
  } else {
    float (*ldsF)[68] = (float(*)[68])shmemF;
    // stage acc+bias (f32) to block tile
#pragma unroll
    for (int f = 0; f < 4; ++f){
#pragma unroll
      for (int i = 0; i < 4; ++i){
        ldsF[w*16 + lg*4 + i][f*16 + lr] = acc[f][i] + bias[c0 + f*16 + lr];
      }
    }
    __syncthreads();
    const float* gsrc = (widx == 2) ? recv : send;
    float* gdst = (widx == 2) ? vrout : vsout;
#pragma unroll
    for (int k = 0; k < 4; ++k){
      int chunk = k*256 + tid;
      int r = chunk >> 4;
      int cc = (chunk & 15) * 4;
      int idx = (m0 + r)*256 + c0 + cc;
      f32x4 v = *(const f32x4*)&ldsF[r][cc];
      f32x4 g = *(const f32x4*)(gsrc + idx);
#pragma unroll
      for (int j = 0; j < 4; ++j) v[j] += g[j];
      *(f32x4*)(gdst + idx) = v;
    }
  }
}

// ---------------- K3b: pack vs per (b,h) into MFMA-B-frag-linear tiles ----------------
// vpk element (bh, kv, d) at (bh*64 + kv/32)*1024 + ((kv>>3)&3)*256 + d*8 + (kv&7)
__global__ __launch_bounds__(256) void k_transV(const float* __restrict__ vsout,
                                                unsigned short* __restrict__ vpk){
  __shared__ float ldsT[32][129];
  int kv0 = blockIdx.x * 128;
  int bh = blockIdx.y;
  int b = bh >> 3, h = bh & 7;
  int tid = threadIdx.x;
#pragma unroll
  for (int p = 0; p < 4; ++p){
    int kvr = p*32 + (tid>>3);
    int dch = (tid&7)*4;
    f32x4 v = *(const f32x4*)(vsout + ((kv0 + kvr)*4 + b)*256 + h*32 + dch);
#pragma unroll
    for (int j = 0; j < 4; ++j) ldsT[dch+j][kvr] = v[j];
  }
  __syncthreads();
#pragma unroll
  for (int rep = 0; rep < 2; ++rep){
    int chunk = rep*256 + tid;
    int d   = chunk & 31;
    int sub = (chunk >> 5) & 3;
    int blk = chunk >> 7;            // 0..3
    int kvb = blk*32 + sub*8;        // local kv base
    ushort8 o;
#pragma unroll
    for (int j = 0; j < 8; ++j) o[j] = f2bf(ldsT[d][kvb + j]);
    *(ushort8*)(vpk + (bh*64 + (kv0>>5) + blk)*1024 + sub*256 + d*8) = o;
  }
}

// ---------------- K4: flash attention; 2 Q-frags per wave (K/V load reuse) ----------------
// 1024 blocks: bh = (bid&7)+8*(bid>>8) (XCD-pinned), qt = (bid>>3)&31 (64 q each).
// Wave w: q-group wq=w&1 (32 rows), kv-half wk=w>>1. Each K/V fragment load
// feeds TWO Q fragments. m=0 softmax => partials additive; combine via LDS.
__global__ __launch_bounds__(256) void k_attn(const unsigned short* __restrict__ qbuf,
                                              const unsigned short* __restrict__ kpk,
                                              const unsigned short* __restrict__ vpk,
                                              const float* __restrict__ vrbuf,
                                              unsigned short* __restrict__ ctx){
  int bid = blockIdx.x;
  int bh  = (bid & 7) + ((bid >> 8) << 3);
  int qt0 = ((bid >> 3) & 31) * 64;
  int b = bh >> 3, h = bh & 7;
  int tid = threadIdx.x;
  int w = tid >> 6, lane = tid & 63;
  int wq = w & 1;        // q 32-group within block
  int wk = w >> 1;       // kv-half
  int lr = lane & 15, lg = lane >> 4;
  int lg4 = lg * 4;

  __shared__ float part[2][2][64][9];   // [wq][qfrag][lane][accO0 x4, accO1 x4, lsum]

  int qbase = qt0 + wq*32;
  // Two Q fragments (pre-scaled by scale*log2e in k_proj)
  bf16x8 qfA = *(const bf16x8*)(qbuf + ((qbase + lr)*BATCH + b)*EMB + h*DHD + lg*8);
  bf16x8 qfB = *(const bf16x8*)(qbuf + ((qbase + 16 + lr)*BATCH + b)*EMB + h*DHD + lg*8);

  // packed per-(b,h) fragment base pointers, offset to this wave's kv half
  const unsigned short* kbase = kpk + bh*65536 + wk*(1024*32) + lr*32 + lg*8;
  const unsigned short* vbase = vpk + bh*65536 + wk*(32*1024) + lg*256 + lr*8;

  f32x4 accA0 = (f32x4){0.f,0.f,0.f,0.f};
  f32x4 accA1 = (f32x4){0.f,0.f,0.f,0.f};
  f32x4 accB0 = (f32x4){0.f,0.f,0.f,0.f};
  f32x4 accB1 = (f32x4){0.f,0.f,0.f,0.f};
  float lsumA = 0.f, lsumB = 0.f;

  bf16x8 kA[4], vA[4], kB[4], vB[4];

  auto loadfr = [&](int kv0, bf16x8* kf, bf16x8* vf){
#pragma unroll
    for (int j = 0; j < 4; ++j)
      kf[j] = *(const bf16x8*)(kbase + (kv0 + j*16)*32);
#pragma unroll
    for (int c = 0; c < 2; ++c)
#pragma unroll
      for (int dh = 0; dh < 2; ++dh)
        vf[c*2+dh] = *(const bf16x8*)(vbase + ((kv0>>5) + c)*1024 + dh*128);
  };

  auto tile_compute = [&](const bf16x8* kf, const bf16x8* vf){
    f32x4 z = (f32x4){0.f,0.f,0.f,0.f};
    f32x4 sA[4], sB[4];
#pragma unroll
    for (int j = 0; j < 4; ++j){
      sA[j] = __builtin_amdgcn_mfma_f32_16x16x32_bf16(kf[j], qfA, z, 0, 0, 0);
      sB[j] = __builtin_amdgcn_mfma_f32_16x16x32_bf16(kf[j], qfB, z, 0, 0, 0);
    }

    float pA[4][4], pB[4][4];
    float psA = 0.f, psB = 0.f;
#pragma unroll
    for (int j = 0; j < 4; ++j){
#pragma unroll
      for (int i = 0; i < 4; ++i){
        pA[j][i] = fexp2(sA[j][i]);
        pB[j][i] = fexp2(sB[j][i]);
      }
      psA += (pA[j][0] + pA[j][1]) + (pA[j][2] + pA[j][3]);
      psB += (pB[j][0] + pB[j][1]) + (pB[j][2] + pB[j][3]);
    }
    lsumA += psA;
    lsumB += psB;

#pragma unroll
    for (int c = 0; c < 2; ++c){
      uint4v dA, dB;
      dA[0] = __builtin_amdgcn_perm(__builtin_bit_cast(unsigned int, pA[c][1]),
                                    __builtin_bit_cast(unsigned int, pA[c][0]), 0x07060302u);
      dA[1] = __builtin_amdgcn_perm(__builtin_bit_cast(unsigned int, pA[c][3]),
                                    __builtin_bit_cast(unsigned int, pA[c][2]), 0x07060302u);
      dA[2] = __builtin_amdgcn_perm(__builtin_bit_cast(unsigned int, pA[c+2][1]),
                                    __builtin_bit_cast(unsigned int, pA[c+2][0]), 0x07060302u);
      dA[3] = __builtin_amdgcn_perm(__builtin_bit_cast(unsigned int, pA[c+2][3]),
                                    __builtin_bit_cast(unsigned int, pA[c+2][2]), 0x07060302u);
      bf16x8 pfA = __builtin_bit_cast(bf16x8, dA);
      accA0 = __builtin_amdgcn_mfma_f32_16x16x32_bf16(pfA, vf[c*2+0], accA0, 0, 0, 0);
      accA1 = __builtin_amdgcn_mfma_f32_16x16x32_bf16(pfA, vf[c*2+1], accA1, 0, 0, 0);
      dB[0] = __builtin_amdgcn_perm(__builtin_bit_cast(unsigned int, pB[c][1]),
                                    __builtin_bit_cast(unsigned int, pB[c][0]), 0x07060302u);
      dB[1] = __builtin_amdgcn_perm(__builtin_bit_cast(unsigned int, pB[c][3]),
                                    __builtin_bit_cast(unsigned int, pB[c][2]), 0x07060302u);
      dB[2] = __builtin_amdgcn_perm(__builtin_bit_cast(unsigned int, pB[c+2][1]),
                                    __builtin_bit_cast(unsigned int, pB[c+2][0]), 0x07060302u);
      dB[3] = __builtin_amdgcn_perm(__builtin_bit_cast(unsigned int, pB[c+2][3]),
                                    __builtin_bit_cast(unsigned int, pB[c+2][2]), 0x07060302u);
      bf16x8 pfB = __builtin_bit_cast(bf16x8, dB);
      accB0 = __builtin_amdgcn_mfma_f32_16x16x32_bf16(pfB, vf[c*2+0], accB0, 0, 0, 0);
      accB1 = __builtin_amdgcn_mfma_f32_16x16x32_bf16(pfB, vf[c*2+1], accB1, 0, 0, 0);
    }
  };

  loadfr(0, kA, vA);
  for (int t = 0; t < 16; t += 2){
    loadfr((t+1)*64, kB, vB);
    tile_compute(kA, vA);
    if (t + 2 < 16) loadfr((t+2)*64, kA, vA);
    tile_compute(kB, vB);
  }

  // reduce lsum across the 4 lane-groups (all lanes then hold row-sum for q=lr)
  lsumA += __shfl_xor(lsumA, 16);
  lsumA += __shfl_xor(lsumA, 32);
  lsumB += __shfl_xor(lsumB, 16);
  lsumB += __shfl_xor(lsumB, 32);

  // combine kv-halves: waves 2-3 publish, waves 0-1 finalize
  if (wk == 1){
#pragma unroll
    for (int i = 0; i < 4; ++i){
      part[wq][0][lane][i]   = accA0[i];
      part[wq][0][lane][4+i] = accA1[i];
      part[wq][1][lane][i]   = accB0[i];
      part[wq][1][lane][4+i] = accB1[i];
    }
    part[wq][0][lane][8] = lsumA;
    part[wq][1][lane][8] = lsumB;
  }
  __syncthreads();
  if (wk == 0){
#pragma unroll
    for (int i = 0; i < 4; ++i){
      accA0[i] += part[wq][0][lane][i];
      accA1[i] += part[wq][0][lane][4+i];
      accB0[i] += part[wq][1][lane][i];
      accB1[i] += part[wq][1][lane][4+i];
    }
    lsumA += part[wq][0][lane][8];
    lsumB += part[wq][1][lane][8];
    float invA = 1.0f / lsumA;
    float invB = 1.0f / lsumB;
#pragma unroll
    for (int i = 0; i < 4; ++i){
      float vinvA = __shfl(invA, lg4 + i);    // 1/lsum for q = qbase+lg4+i
      float vinvB = __shfl(invB, lg4 + i);    // 1/lsum for q = qbase+16+lg4+i
      int qA = qbase + lg4 + i;
      int idxA = (qA * BATCH + b) * EMB + h*DHD + lr;
      ctx[idxA]      = f2bf(accA0[i] * vinvA + vrbuf[idxA]);
      ctx[idxA + 16] = f2bf(accA1[i] * vinvA + vrbuf[idxA + 16]);
      int qB = qbase + 16 + lg4 + i;
      int idxB = (qB * BATCH + b) * EMB + h*DHD + lr;
      ctx[idxB]      = f2bf(accB0[i] * vinvB + vrbuf[idxB]);
      ctx[idxB + 16] = f2bf(accB1[i] * vinvB + vrbuf[idxB + 16]);
    }
  }
}

// ---------------- K5: out = x + ctx @ Wo + bo  (f32 out) ----------------
__global__ __launch_bounds__(256) void k_out(const unsigned short* __restrict__ ctx,
                                             const unsigned short* __restrict__ wto,
                                             const float* __restrict__ bo,
                                             const float* __restrict__ x,
                                             float* __restrict__ out0){
  int m0 = blockIdx.x * 64;
  int c0 = blockIdx.y * 64;
  int tid = threadIdx.x;
  int w = tid >> 6, lane = tid & 63;
  int lr = lane & 15, lg = lane >> 4;

  const unsigned short* aptr = ctx + (m0 + w*16 + lr) * 256 + lg * 8;

  f32x4 acc[4];
#pragma unroll
  for (int f = 0; f < 4; ++f) acc[f] = (f32x4){0.f, 0.f, 0.f, 0.f};

#pragma unroll
  for (int k0 = 0; k0 < 256; k0 += 32){
    bf16x8 af = *(const bf16x8*)(aptr + k0);
#pragma unroll
    for (int f = 0; f < 4; ++f){
      bf16x8 bfrag = *(const bf16x8*)(wto + (c0 + f*16 + lr) * 256 + k0 + lg * 8);
      acc[f] = __builtin_amdgcn_mfma_f32_16x16x32_bf16(af, bfrag, acc[f], 0, 0, 0);
    }
  }

#pragma unroll
  for (int f = 0; f < 4; ++f){
#pragma unroll
    for (int i = 0; i < 4; ++i){
      int m = m0 + w*16 + lg*4 + i;
      int c = c0 + f*16 + lr;
      int idx = m * 256 + c;
      out0[idx] = acc[f][i] + bo[c] + x[idx];
    }
  }
}

extern "C" void kernel_launch(void* const* d_in, const int* in_sizes, int n_in,
                              void* d_out, int out_size, void* d_ws, size_t ws_size,
                              hipStream_t stream){
  const float* x    = (const float*)d_in[0];
  const float* qp   = (const float*)d_in[1];
  const float* recv = (const float*)d_in[2];
  const float* send = (const float*)d_in[3];
  const float* Wq   = (const float*)d_in[4];
  const float* bq   = (const float*)d_in[5];
  const float* Wk   = (const float*)d_in[6];
  const float* bk   = (const float*)d_in[7];
  const float* Wr   = (const float*)d_in[8];
  const float* br   = (const float*)d_in[9];
  const float* Wsv  = (const float*)d_in[10];
  const float* bsv  = (const float*)d_in[11];
  const float* Wo   = (const float*)d_in[12];
  const float* bo   = (const float*)d_in[13];

  float* out0  = (float*)d_out;
  float* vrout = out0 + NBE;
  float* vsout = out0 + 2*NBE;

  unsigned short* ws   = (unsigned short*)d_ws;
  unsigned short* qin  = ws;                 // reused as ctx after proj
  unsigned short* qbuf = ws + NBE;
  unsigned short* kpk  = ws + 2*NBE;         // [32 bh][2048 kv perm][32 d]
  unsigned short* vpk  = ws + 3*NBE;         // [32 bh][64 tiles][1024] frag-linear
  unsigned short* wt   = ws + 4*NBE;         // 5 * 65536

  hipLaunchKernelGGL(k_add, dim3(NBE/8/256), dim3(256), 0, stream, x, qp, qin);
  hipLaunchKernelGGL(k_transW, dim3(4, 4, 5), dim3(256), 0, stream, Wq, Wk, Wr, Wsv, Wo, wt);
  hipLaunchKernelGGL(k_proj, dim3(128, 16), dim3(256), 0, stream,
                     qin, wt, bq, bk, br, bsv, recv, send, qbuf, kpk, vrout, vsout);
  hipLaunchKernelGGL(k_transV, dim3(16, 32), dim3(256), 0, stream, vsout, vpk);
  hipLaunchKernelGGL(k_attn, dim3(1024), dim3(256), 0, stream,
                     qbuf, kpk, vpk, vrout, qin /*ctx*/);
  hipLaunchKernelGGL(k_out, dim3(128, 4), dim3(256), 0, stream,
                     qin /*ctx*/, wt + 4*65536, bo, x, out0);
}

// Round 15
// 81.254 us; speedup vs baseline: 1.2889x; 1.2889x over previous
//
#include <hip/hip_runtime.h>
#include <hip/hip_bf16.h>

#define NTOK 2048
#define BATCH 4
#define EMB 256
#define NH 8
#define DHD 32
#define MROWS (NTOK*BATCH)      // 8192
#define NBE (MROWS*EMB)         // 2097152

typedef __attribute__((ext_vector_type(8))) __bf16 bf16x8;
typedef __attribute__((ext_vector_type(4))) float f32x4;
typedef __attribute__((ext_vector_type(8))) unsigned short ushort8;
typedef __attribute__((ext_vector_type(4))) unsigned int uint4v;

__device__ __forceinline__ unsigned short f2bf(float f){
  unsigned int u = __builtin_bit_cast(unsigned int, f);
  u += 0x7fffu + ((u >> 16) & 1u);
  return (unsigned short)(u >> 16);
}
__device__ __forceinline__ float fexp2(float x){
#if __has_builtin(__builtin_amdgcn_exp2f)
  return __builtin_amdgcn_exp2f(x);
#else
  return exp2f(x);
#endif
}

// fold 1/sqrt(32) * log2(e) into q so scores are in log2 domain
#define QSC (0.17677669529663687f * 1.4426950408889634f)

// Fragment-linear packing for [R][256] matrices:
//   pos(r,k) = (r>>4)*4096 + (k>>5)*512 + (r&15)*32 + (k&31)
// => a 16x32 MFMA A/B fragment load (lanes lr,lg at lr*32+lg*8) is a fully
//    contiguous 1KB wave transaction instead of 16 scattered 64B segments.

// ---------------- K1: qpk = packed bf16(x + query_pos) ----------------
__global__ __launch_bounds__(256) void k_add(const float* __restrict__ x,
                                             const float* __restrict__ qp,
                                             unsigned short* __restrict__ qpk){
  int t = blockIdx.x * 256 + threadIdx.x;
  int ppos = t * 8;
  int tile = ppos >> 12;
  int rem  = ppos & 4095;
  int kc   = rem >> 9;
  int row  = (rem >> 5) & 15;
  int kk   = rem & 31;               // multiple of 8
  int src  = (tile*16 + row)*256 + kc*32 + kk;
  f32x4 a0 = *(const f32x4*)(x + src);
  f32x4 a1 = *(const f32x4*)(x + src + 4);
  f32x4 b0 = *(const f32x4*)(qp + src);
  f32x4 b1 = *(const f32x4*)(qp + src + 4);
  ushort8 o;
#pragma unroll
  for (int j = 0; j < 4; ++j){
    o[j]   = f2bf(a0[j] + b0[j]);
    o[j+4] = f2bf(a1[j] + b1[j]);
  }
  *(ushort8*)(qpk + ppos) = o;
}

// ---------------- K2: transpose+cast 5 weights into packed layout ----------------
__global__ __launch_bounds__(256) void k_transW(const float* __restrict__ s0,
                                                const float* __restrict__ s1,
                                                const float* __restrict__ s2,
                                                const float* __restrict__ s3,
                                                const float* __restrict__ s4,
                                                unsigned short* __restrict__ wt){
  const float* srcs[5] = {s0, s1, s2, s3, s4};
  __shared__ float lds[64][65];
  int wi = blockIdx.z;
  int k0 = blockIdx.x * 64;
  int n0 = blockIdx.y * 64;
  int tid = threadIdx.x;
  const float* src = srcs[wi];
#pragma unroll
  for (int p = 0; p < 4; ++p){
    int r = p*16 + (tid>>4);
    int c = (tid&15)*4;
    f32x4 v = *(const f32x4*)(src + (k0+r)*256 + n0 + c);
#pragma unroll
    for (int j = 0; j < 4; ++j) lds[r][c+j] = v[j];
  }
  __syncthreads();
#pragma unroll
  for (int p = 0; p < 4; ++p){
    int nr = p*16 + (tid>>4);
    int kc = (tid&15)*4;
    unsigned long long pk = 0;
#pragma unroll
    for (int j = 0; j < 4; ++j)
      pk |= ((unsigned long long)f2bf(lds[kc+j][nr])) << (16*j);
    int n_g = n0 + nr, k_g = k0 + kc;
    int pos = (n_g>>4)*4096 + (k_g>>5)*512 + (n_g&15)*32 + (k_g&31);
    *(unsigned long long*)(wt + wi*65536 + pos) = pk;
  }
}

// ---------------- K3: fused 4-way projection GEMM (packed operands) ----------------
__global__ __launch_bounds__(256) void k_proj(const unsigned short* __restrict__ qpk,
                                              const unsigned short* __restrict__ wt,
                                              const float* __restrict__ bq,
                                              const float* __restrict__ bk,
                                              const float* __restrict__ br,
                                              const float* __restrict__ bs,
                                              const float* __restrict__ recv,
                                              const float* __restrict__ send,
                                              unsigned short* __restrict__ qbuf,
                                              unsigned short* __restrict__ kpk,
                                              float* __restrict__ vrout,
                                              float* __restrict__ vsout){
  int m0 = blockIdx.x * 64;
  int gc = blockIdx.y * 64;
  int widx = gc >> 8;
  int c0 = gc & 255;
  int tid = threadIdx.x;
  int w = tid >> 6, lane = tid & 63;
  int lr = lane & 15, lg = lane >> 4;

  __shared__ __align__(16) float shmemF[64*68];   // aliased: bf16 st view or f32 tile

  const unsigned short* apk = qpk + (m0/16 + w)*4096 + lr*32 + lg*8;
  const unsigned short* bpk = wt + widx*65536 + (c0/16)*4096 + lr*32 + lg*8;

  f32x4 acc[4];
#pragma unroll
  for (int f = 0; f < 4; ++f) acc[f] = (f32x4){0.f, 0.f, 0.f, 0.f};

#pragma unroll
  for (int k0 = 0; k0 < 256; k0 += 32){
    int kb = (k0 >> 5) * 512;
    bf16x8 af = *(const bf16x8*)(apk + kb);
#pragma unroll
    for (int f = 0; f < 4; ++f){
      bf16x8 bfrag = *(const bf16x8*)(bpk + f*4096 + kb);
      acc[f] = __builtin_amdgcn_mfma_f32_16x16x32_bf16(af, bfrag, acc[f], 0, 0, 0);
    }
  }

  const float* bias = (widx == 0) ? bq : (widx == 1) ? bk : (widx == 2) ? br : bs;

  if (widx <= 1){
    unsigned short (*st)[16][72] = (unsigned short(*)[16][72])shmemF;
    // stage bf16 tile to this wave's LDS slab (same-wave produce/consume, no barrier)
#pragma unroll
    for (int f = 0; f < 4; ++f){
#pragma unroll
      for (int i = 0; i < 4; ++i){
        int c = c0 + f*16 + lr;
        float v = acc[f][i] + bias[c];
        st[w][lg*4+i][f*16+lr] = f2bf(widx == 0 ? v * QSC : v);
      }
    }
    if (widx == 0){
      int r = lane >> 2, co = (lane & 3) * 16;
      ushort8 a0 = *(ushort8*)&st[w][r][co];
      ushort8 a1 = *(ushort8*)&st[w][r][co + 8];
      unsigned short* dst = qbuf + (m0 + w*16 + r) * 256 + c0 + co;
      *(ushort8*)dst = a0;
      *(ushort8*)(dst + 8) = a1;
    } else {
      int cid = lane >> 3, s = lane & 7;
      int bb = cid >> 1, hr = cid & 1;
      int toko = s >> 1, dp = (s & 1) * 16;
      ushort8 a0 = *(ushort8*)&st[w][toko*4 + bb][hr*32 + dp];
      ushort8 a1 = *(ushort8*)&st[w][toko*4 + bb][hr*32 + dp + 8];
      int h  = (c0 >> 5) + hr;
      int n0 = (m0 + w*16) >> 2;          // first token of this wave's tile (mult of 4)
      int t0 = n0 & 63;
      int p0 = (((t0>>5)&1)<<4) + (((t0>>2)&1)<<5) + (((t0>>3)&3)<<2);
      unsigned short* dst = kpk + (bb*8 + h)*65536 + ((n0 & ~63) + p0 + toko)*32 + dp;
      *(ushort8*)dst = a0;
      *(ushort8*)(dst + 8) = a1;
    }
  } else {
    float (*ldsF)[68] = (float(*)[68])shmemF;
    // stage acc+bias (f32) to block tile
#pragma unroll
    for (int f = 0; f < 4; ++f){
#pragma unroll
      for (int i = 0; i < 4; ++i){
        ldsF[w*16 + lg*4 + i][f*16 + lr] = acc[f][i] + bias[c0 + f*16 + lr];
      }
    }
    __syncthreads();
    const float* gsrc = (widx == 2) ? recv : send;
    float* gdst = (widx == 2) ? vrout : vsout;
#pragma unroll
    for (int k = 0; k < 4; ++k){
      int chunk = k*256 + tid;
      int r = chunk >> 4;
      int cc = (chunk & 15) * 4;
      int idx = (m0 + r)*256 + c0 + cc;
      f32x4 v = *(const f32x4*)&ldsF[r][cc];
      f32x4 g = *(const f32x4*)(gsrc + idx);
#pragma unroll
      for (int j = 0; j < 4; ++j) v[j] += g[j];
      *(f32x4*)(gdst + idx) = v;
    }
  }
}

// ---------------- K3b: pack vs per (b,h) into MFMA-B-frag-linear tiles ----------------
// vpk element (bh, kv, d) at (bh*64 + kv/32)*1024 + ((kv>>3)&3)*256 + d*8 + (kv&7)
__global__ __launch_bounds__(256) void k_transV(const float* __restrict__ vsout,
                                                unsigned short* __restrict__ vpk){
  __shared__ float ldsT[32][129];
  int kv0 = blockIdx.x * 128;
  int bh = blockIdx.y;
  int b = bh >> 3, h = bh & 7;
  int tid = threadIdx.x;
#pragma unroll
  for (int p = 0; p < 4; ++p){
    int kvr = p*32 + (tid>>3);
    int dch = (tid&7)*4;
    f32x4 v = *(const f32x4*)(vsout + ((kv0 + kvr)*4 + b)*256 + h*32 + dch);
#pragma unroll
    for (int j = 0; j < 4; ++j) ldsT[dch+j][kvr] = v[j];
  }
  __syncthreads();
#pragma unroll
  for (int rep = 0; rep < 2; ++rep){
    int chunk = rep*256 + tid;
    int d   = chunk & 31;
    int sub = (chunk >> 5) & 3;
    int blk = chunk >> 7;            // 0..3
    int kvb = blk*32 + sub*8;        // local kv base
    ushort8 o;
#pragma unroll
    for (int j = 0; j < 8; ++j) o[j] = f2bf(ldsT[d][kvb + j]);
    *(ushort8*)(vpk + (bh*64 + (kv0>>5) + blk)*1024 + sub*256 + d*8) = o;
  }
}

// ---------------- K4: flash attention; 2 Q-frags per wave; packed ctx out ----------------
__global__ __launch_bounds__(256) void k_attn(const unsigned short* __restrict__ qbuf,
                                              const unsigned short* __restrict__ kpk,
                                              const unsigned short* __restrict__ vpk,
                                              const float* __restrict__ vrbuf,
                                              unsigned short* __restrict__ ctx){
  int bid = blockIdx.x;
  int bh  = (bid & 7) + ((bid >> 8) << 3);
  int qt0 = ((bid >> 3) & 31) * 64;
  int b = bh >> 3, h = bh & 7;
  int tid = threadIdx.x;
  int w = tid >> 6, lane = tid & 63;
  int wq = w & 1;        // q 32-group within block
  int wk = w >> 1;       // kv-half
  int lr = lane & 15, lg = lane >> 4;
  int lg4 = lg * 4;

  __shared__ float part[2][2][64][9];   // [wq][qfrag][lane][accO0 x4, accO1 x4, lsum]

  int qbase = qt0 + wq*32;
  // Two Q fragments (pre-scaled by scale*log2e in k_proj)
  bf16x8 qfA = *(const bf16x8*)(qbuf + ((qbase + lr)*BATCH + b)*EMB + h*DHD + lg*8);
  bf16x8 qfB = *(const bf16x8*)(qbuf + ((qbase + 16 + lr)*BATCH + b)*EMB + h*DHD + lg*8);

  // packed per-(b,h) fragment base pointers, offset to this wave's kv half
  const unsigned short* kbase = kpk + bh*65536 + wk*(1024*32) + lr*32 + lg*8;
  const unsigned short* vbase = vpk + bh*65536 + wk*(32*1024) + lg*256 + lr*8;

  f32x4 accA0 = (f32x4){0.f,0.f,0.f,0.f};
  f32x4 accA1 = (f32x4){0.f,0.f,0.f,0.f};
  f32x4 accB0 = (f32x4){0.f,0.f,0.f,0.f};
  f32x4 accB1 = (f32x4){0.f,0.f,0.f,0.f};
  float lsumA = 0.f, lsumB = 0.f;

  bf16x8 kA[4], vA[4], kB[4], vB[4];

  auto loadfr = [&](int kv0, bf16x8* kf, bf16x8* vf){
#pragma unroll
    for (int j = 0; j < 4; ++j)
      kf[j] = *(const bf16x8*)(kbase + (kv0 + j*16)*32);
#pragma unroll
    for (int c = 0; c < 2; ++c)
#pragma unroll
      for (int dh = 0; dh < 2; ++dh)
        vf[c*2+dh] = *(const bf16x8*)(vbase + ((kv0>>5) + c)*1024 + dh*128);
  };

  auto tile_compute = [&](const bf16x8* kf, const bf16x8* vf){
    f32x4 z = (f32x4){0.f,0.f,0.f,0.f};
    f32x4 sA[4], sB[4];
#pragma unroll
    for (int j = 0; j < 4; ++j){
      sA[j] = __builtin_amdgcn_mfma_f32_16x16x32_bf16(kf[j], qfA, z, 0, 0, 0);
      sB[j] = __builtin_amdgcn_mfma_f32_16x16x32_bf16(kf[j], qfB, z, 0, 0, 0);
    }

    float pA[4][4], pB[4][4];
    float psA = 0.f, psB = 0.f;
#pragma unroll
    for (int j = 0; j < 4; ++j){
#pragma unroll
      for (int i = 0; i < 4; ++i){
        pA[j][i] = fexp2(sA[j][i]);
        pB[j][i] = fexp2(sB[j][i]);
      }
      psA += (pA[j][0] + pA[j][1]) + (pA[j][2] + pA[j][3]);
      psB += (pB[j][0] + pB[j][1]) + (pB[j][2] + pB[j][3]);
    }
    lsumA += psA;
    lsumB += psB;

#pragma unroll
    for (int c = 0; c < 2; ++c){
      uint4v dA, dB;
      dA[0] = __builtin_amdgcn_perm(__builtin_bit_cast(unsigned int, pA[c][1]),
                                    __builtin_bit_cast(unsigned int, pA[c][0]), 0x07060302u);
      dA[1] = __builtin_amdgcn_perm(__builtin_bit_cast(unsigned int, pA[c][3]),
                                    __builtin_bit_cast(unsigned int, pA[c][2]), 0x07060302u);
      dA[2] = __builtin_amdgcn_perm(__builtin_bit_cast(unsigned int, pA[c+2][1]),
                                    __builtin_bit_cast(unsigned int, pA[c+2][0]), 0x07060302u);
      dA[3] = __builtin_amdgcn_perm(__builtin_bit_cast(unsigned int, pA[c+2][3]),
                                    __builtin_bit_cast(unsigned int, pA[c+2][2]), 0x07060302u);
      bf16x8 pfA = __builtin_bit_cast(bf16x8, dA);
      accA0 = __builtin_amdgcn_mfma_f32_16x16x32_bf16(pfA, vf[c*2+0], accA0, 0, 0, 0);
      accA1 = __builtin_amdgcn_mfma_f32_16x16x32_bf16(pfA, vf[c*2+1], accA1, 0, 0, 0);
      dB[0] = __builtin_amdgcn_perm(__builtin_bit_cast(unsigned int, pB[c][1]),
                                    __builtin_bit_cast(unsigned int, pB[c][0]), 0x07060302u);
      dB[1] = __builtin_amdgcn_perm(__builtin_bit_cast(unsigned int, pB[c][3]),
                                    __builtin_bit_cast(unsigned int, pB[c][2]), 0x07060302u);
      dB[2] = __builtin_amdgcn_perm(__builtin_bit_cast(unsigned int, pB[c+2][1]),
                                    __builtin_bit_cast(unsigned int, pB[c+2][0]), 0x07060302u);
      dB[3] = __builtin_amdgcn_perm(__builtin_bit_cast(unsigned int, pB[c+2][3]),
                                    __builtin_bit_cast(unsigned int, pB[c+2][2]), 0x07060302u);
      bf16x8 pfB = __builtin_bit_cast(bf16x8, dB);
      accB0 = __builtin_amdgcn_mfma_f32_16x16x32_bf16(pfB, vf[c*2+0], accB0, 0, 0, 0);
      accB1 = __builtin_amdgcn_mfma_f32_16x16x32_bf16(pfB, vf[c*2+1], accB1, 0, 0, 0);
    }
  };

  loadfr(0, kA, vA);
  for (int t = 0; t < 16; t += 2){
    loadfr((t+1)*64, kB, vB);
    tile_compute(kA, vA);
    if (t + 2 < 16) loadfr((t+2)*64, kA, vA);
    tile_compute(kB, vB);
  }

  // reduce lsum across the 4 lane-groups (all lanes then hold row-sum for q=lr)
  lsumA += __shfl_xor(lsumA, 16);
  lsumA += __shfl_xor(lsumA, 32);
  lsumB += __shfl_xor(lsumB, 16);
  lsumB += __shfl_xor(lsumB, 32);

  // combine kv-halves: waves 2-3 publish, waves 0-1 finalize
  if (wk == 1){
#pragma unroll
    for (int i = 0; i < 4; ++i){
      part[wq][0][lane][i]   = accA0[i];
      part[wq][0][lane][4+i] = accA1[i];
      part[wq][1][lane][i]   = accB0[i];
      part[wq][1][lane][4+i] = accB1[i];
    }
    part[wq][0][lane][8] = lsumA;
    part[wq][1][lane][8] = lsumB;
  }
  __syncthreads();
  if (wk == 0){
#pragma unroll
    for (int i = 0; i < 4; ++i){
      accA0[i] += part[wq][0][lane][i];
      accA1[i] += part[wq][0][lane][4+i];
      accB0[i] += part[wq][1][lane][i];
      accB1[i] += part[wq][1][lane][4+i];
    }
    lsumA += part[wq][0][lane][8];
    lsumB += part[wq][1][lane][8];
    float invA = 1.0f / lsumA;
    float invB = 1.0f / lsumB;
    // ctx written in packed layout: pos(m,col) with m = q*4+b, col = h*32+d
#pragma unroll
    for (int i = 0; i < 4; ++i){
      float vinvA = __shfl(invA, lg4 + i);
      float vinvB = __shfl(invB, lg4 + i);
      int qA = qbase + lg4 + i;
      int mA = qA*4 + b;
      int idxA = mA*256 + h*DHD + lr;                          // row-major idx for vrbuf
      int posA = (qA>>2)*4096 + h*512 + (4*(qA&3)+b)*32 + lr;  // packed idx for ctx
      ctx[posA]      = f2bf(accA0[i] * vinvA + vrbuf[idxA]);
      ctx[posA + 16] = f2bf(accA1[i] * vinvA + vrbuf[idxA + 16]);
      int qB = qbase + 16 + lg4 + i;
      int mB = qB*4 + b;
      int idxB = mB*256 + h*DHD + lr;
      int posB = (qB>>2)*4096 + h*512 + (4*(qB&3)+b)*32 + lr;
      ctx[posB]      = f2bf(accB0[i] * vinvB + vrbuf[idxB]);
      ctx[posB + 16] = f2bf(accB1[i] * vinvB + vrbuf[idxB + 16]);
    }
  }
}

// ---------------- K5: out = x + ctx @ Wo + bo (packed operands, staged epilogue) ----------------
__global__ __launch_bounds__(256) void k_out(const unsigned short* __restrict__ ctx,
                                             const unsigned short* __restrict__ wt,
                                             const float* __restrict__ bo,
                                             const float* __restrict__ x,
                                             float* __restrict__ out0){
  int m0 = blockIdx.x * 64;
  int c0 = blockIdx.y * 64;
  int tid = threadIdx.x;
  int w = tid >> 6, lane = tid & 63;
  int lr = lane & 15, lg = lane >> 4;

  __shared__ __align__(16) float ldsF[64][68];

  const unsigned short* apk = ctx + (m0/16 + w)*4096 + lr*32 + lg*8;
  const unsigned short* bpk = wt + 4*65536 + (c0/16)*4096 + lr*32 + lg*8;

  f32x4 acc[4];
#pragma unroll
  for (int f = 0; f < 4; ++f) acc[f] = (f32x4){0.f, 0.f, 0.f, 0.f};

#pragma unroll
  for (int k0 = 0; k0 < 256; k0 += 32){
    int kb = (k0 >> 5) * 512;
    bf16x8 af = *(const bf16x8*)(apk + kb);
#pragma unroll
    for (int f = 0; f < 4; ++f){
      bf16x8 bfrag = *(const bf16x8*)(bpk + f*4096 + kb);
      acc[f] = __builtin_amdgcn_mfma_f32_16x16x32_bf16(af, bfrag, acc[f], 0, 0, 0);
    }
  }

  // stage acc + bo to LDS, then vectorized RMW with x
#pragma unroll
  for (int f = 0; f < 4; ++f){
#pragma unroll
    for (int i = 0; i < 4; ++i){
      ldsF[w*16 + lg*4 + i][f*16 + lr] = acc[f][i] + bo[c0 + f*16 + lr];
    }
  }
  __syncthreads();
#pragma unroll
  for (int k = 0; k < 4; ++k){
    int chunk = k*256 + tid;
    int r = chunk >> 4;
    int cc = (chunk & 15) * 4;
    int idx = (m0 + r)*256 + c0 + cc;
    f32x4 v = *(const f32x4*)&ldsF[r][cc];
    f32x4 g = *(const f32x4*)(x + idx);
#pragma unroll
    for (int j = 0; j < 4; ++j) v[j] += g[j];
    *(f32x4*)(out0 + idx) = v;
  }
}

extern "C" void kernel_launch(void* const* d_in, const int* in_sizes, int n_in,
                              void* d_out, int out_size, void* d_ws, size_t ws_size,
                              hipStream_t stream){
  const float* x    = (const float*)d_in[0];
  const float* qp   = (const float*)d_in[1];
  const float* recv = (const float*)d_in[2];
  const float* send = (const float*)d_in[3];
  const float* Wq   = (const float*)d_in[4];
  const float* bq   = (const float*)d_in[5];
  const float* Wk   = (const float*)d_in[6];
  const float* bk   = (const float*)d_in[7];
  const float* Wr   = (const float*)d_in[8];
  const float* br   = (const float*)d_in[9];
  const float* Wsv  = (const float*)d_in[10];
  const float* bsv  = (const float*)d_in[11];
  const float* Wo   = (const float*)d_in[12];
  const float* bo   = (const float*)d_in[13];

  float* out0  = (float*)d_out;
  float* vrout = out0 + NBE;
  float* vsout = out0 + 2*NBE;

  unsigned short* ws   = (unsigned short*)d_ws;
  unsigned short* qin  = ws;                 // packed; reused as packed ctx after proj
  unsigned short* qbuf = ws + NBE;
  unsigned short* kpk  = ws + 2*NBE;         // [32 bh][2048 kv perm][32 d]
  unsigned short* vpk  = ws + 3*NBE;         // [32 bh][64 tiles][1024] frag-linear
  unsigned short* wt   = ws + 4*NBE;         // 5 * 65536, packed

  hipLaunchKernelGGL(k_add, dim3(NBE/8/256), dim3(256), 0, stream, x, qp, qin);
  hipLaunchKernelGGL(k_transW, dim3(4, 4, 5), dim3(256), 0, stream, Wq, Wk, Wr, Wsv, Wo, wt);
  hipLaunchKernelGGL(k_proj, dim3(128, 16), dim3(256), 0, stream,
                     qin, wt, bq, bk, br, bsv, recv, send, qbuf, kpk, vrout, vsout);
  hipLaunchKernelGGL(k_transV, dim3(16, 32), dim3(256), 0, stream, vsout, vpk);
  hipLaunchKernelGGL(k_attn, dim3(1024), dim3(256), 0, stream,
                     qbuf, kpk, vpk, vrout, qin /*ctx, packed*/);
  hipLaunchKernelGGL(k_out, dim3(128, 4), dim3(256), 0, stream,
                     qin /*ctx*/, wt, bo, x, out0);
}

// Round 16
// 80.350 us; speedup vs baseline: 1.3034x; 1.0112x over previous
//
#include <hip/hip_runtime.h>
#include <hip/hip_bf16.h>

#define NTOK 2048
#define BATCH 4
#define EMB 256
#define NH 8
#define DHD 32
#define MROWS (NTOK*BATCH)      // 8192
#define NBE (MROWS*EMB)         // 2097152

typedef __attribute__((ext_vector_type(8))) __bf16 bf16x8;
typedef __attribute__((ext_vector_type(4))) float f32x4;
typedef __attribute__((ext_vector_type(8))) unsigned short ushort8;
typedef __attribute__((ext_vector_type(4))) unsigned int uint4v;

__device__ __forceinline__ unsigned short f2bf(float f){
  unsigned int u = __builtin_bit_cast(unsigned int, f);
  u += 0x7fffu + ((u >> 16) & 1u);
  return (unsigned short)(u >> 16);
}
__device__ __forceinline__ float fexp2(float x){
#if __has_builtin(__builtin_amdgcn_exp2f)
  return __builtin_amdgcn_exp2f(x);
#else
  return exp2f(x);
#endif
}

// fold 1/sqrt(32) * log2(e) into q so scores are in log2 domain
#define QSC (0.17677669529663687f * 1.4426950408889634f)

// Fragment-linear packing for [R][256] matrices:
//   pos(r,k) = (r>>4)*4096 + (k>>5)*512 + (r&15)*32 + (k&31)

// ---------------- K1: qpk = packed bf16(x + query_pos) ----------------
__global__ __launch_bounds__(256) void k_add(const float* __restrict__ x,
                                             const float* __restrict__ qp,
                                             unsigned short* __restrict__ qpk){
  int t = blockIdx.x * 256 + threadIdx.x;
  int ppos = t * 8;
  int tile = ppos >> 12;
  int rem  = ppos & 4095;
  int kc   = rem >> 9;
  int row  = (rem >> 5) & 15;
  int kk   = rem & 31;               // multiple of 8
  int src  = (tile*16 + row)*256 + kc*32 + kk;
  f32x4 a0 = *(const f32x4*)(x + src);
  f32x4 a1 = *(const f32x4*)(x + src + 4);
  f32x4 b0 = *(const f32x4*)(qp + src);
  f32x4 b1 = *(const f32x4*)(qp + src + 4);
  ushort8 o;
#pragma unroll
  for (int j = 0; j < 4; ++j){
    o[j]   = f2bf(a0[j] + b0[j]);
    o[j+4] = f2bf(a1[j] + b1[j]);
  }
  *(ushort8*)(qpk + ppos) = o;
}

// ---------------- K2: transpose+cast 5 weights into packed layout ----------------
__global__ __launch_bounds__(256) void k_transW(const float* __restrict__ s0,
                                                const float* __restrict__ s1,
                                                const float* __restrict__ s2,
                                                const float* __restrict__ s3,
                                                const float* __restrict__ s4,
                                                unsigned short* __restrict__ wt){
  const float* srcs[5] = {s0, s1, s2, s3, s4};
  __shared__ float lds[64][65];
  int wi = blockIdx.z;
  int k0 = blockIdx.x * 64;
  int n0 = blockIdx.y * 64;
  int tid = threadIdx.x;
  const float* src = srcs[wi];
#pragma unroll
  for (int p = 0; p < 4; ++p){
    int r = p*16 + (tid>>4);
    int c = (tid&15)*4;
    f32x4 v = *(const f32x4*)(src + (k0+r)*256 + n0 + c);
#pragma unroll
    for (int j = 0; j < 4; ++j) lds[r][c+j] = v[j];
  }
  __syncthreads();
#pragma unroll
  for (int p = 0; p < 4; ++p){
    int nr = p*16 + (tid>>4);
    int kc = (tid&15)*4;
    unsigned long long pk = 0;
#pragma unroll
    for (int j = 0; j < 4; ++j)
      pk |= ((unsigned long long)f2bf(lds[kc+j][nr])) << (16*j);
    int n_g = n0 + nr, k_g = k0 + kc;
    int pos = (n_g>>4)*4096 + (k_g>>5)*512 + (n_g&15)*32 + (k_g&31);
    *(unsigned long long*)(wt + wi*65536 + pos) = pk;
  }
}

// ---------------- K3: fused 4-way projection GEMM (packed operands) ----------------
__global__ __launch_bounds__(256) void k_proj(const unsigned short* __restrict__ qpk,
                                              const unsigned short* __restrict__ wt,
                                              const float* __restrict__ bq,
                                              const float* __restrict__ bk,
                                              const float* __restrict__ br,
                                              const float* __restrict__ bs,
                                              const float* __restrict__ recv,
                                              const float* __restrict__ send,
                                              unsigned short* __restrict__ qbuf,
                                              unsigned short* __restrict__ kpk,
                                              float* __restrict__ vrout,
                                              float* __restrict__ vsout){
  int m0 = blockIdx.x * 64;
  int gc = blockIdx.y * 64;
  int widx = gc >> 8;
  int c0 = gc & 255;
  int tid = threadIdx.x;
  int w = tid >> 6, lane = tid & 63;
  int lr = lane & 15, lg = lane >> 4;

  __shared__ __align__(16) float shmemF[64*68];   // aliased: bf16 st view or f32 tile

  const unsigned short* apk = qpk + (m0/16 + w)*4096 + lr*32 + lg*8;
  const unsigned short* bpk = wt + widx*65536 + (c0/16)*4096 + lr*32 + lg*8;

  f32x4 acc[4];
#pragma unroll
  for (int f = 0; f < 4; ++f) acc[f] = (f32x4){0.f, 0.f, 0.f, 0.f};

#pragma unroll
  for (int k0 = 0; k0 < 256; k0 += 32){
    int kb = (k0 >> 5) * 512;
    bf16x8 af = *(const bf16x8*)(apk + kb);
#pragma unroll
    for (int f = 0; f < 4; ++f){
      bf16x8 bfrag = *(const bf16x8*)(bpk + f*4096 + kb);
      acc[f] = __builtin_amdgcn_mfma_f32_16x16x32_bf16(af, bfrag, acc[f], 0, 0, 0);
    }
  }

  const float* bias = (widx == 0) ? bq : (widx == 1) ? bk : (widx == 2) ? br : bs;

  if (widx <= 1){
    unsigned short (*st)[16][72] = (unsigned short(*)[16][72])shmemF;
#pragma unroll
    for (int f = 0; f < 4; ++f){
#pragma unroll
      for (int i = 0; i < 4; ++i){
        int c = c0 + f*16 + lr;
        float v = acc[f][i] + bias[c];
        st[w][lg*4+i][f*16+lr] = f2bf(widx == 0 ? v * QSC : v);
      }
    }
    if (widx == 0){
      int r = lane >> 2, co = (lane & 3) * 16;
      ushort8 a0 = *(ushort8*)&st[w][r][co];
      ushort8 a1 = *(ushort8*)&st[w][r][co + 8];
      unsigned short* dst = qbuf + (m0 + w*16 + r) * 256 + c0 + co;
      *(ushort8*)dst = a0;
      *(ushort8*)(dst + 8) = a1;
    } else {
      int cid = lane >> 3, s = lane & 7;
      int bb = cid >> 1, hr = cid & 1;
      int toko = s >> 1, dp = (s & 1) * 16;
      ushort8 a0 = *(ushort8*)&st[w][toko*4 + bb][hr*32 + dp];
      ushort8 a1 = *(ushort8*)&st[w][toko*4 + bb][hr*32 + dp + 8];
      int h  = (c0 >> 5) + hr;
      int n0 = (m0 + w*16) >> 2;
      int t0 = n0 & 63;
      int p0 = (((t0>>5)&1)<<4) + (((t0>>2)&1)<<5) + (((t0>>3)&3)<<2);
      unsigned short* dst = kpk + (bb*8 + h)*65536 + ((n0 & ~63) + p0 + toko)*32 + dp;
      *(ushort8*)dst = a0;
      *(ushort8*)(dst + 8) = a1;
    }
  } else {
    float (*ldsF)[68] = (float(*)[68])shmemF;
#pragma unroll
    for (int f = 0; f < 4; ++f){
#pragma unroll
      for (int i = 0; i < 4; ++i){
        ldsF[w*16 + lg*4 + i][f*16 + lr] = acc[f][i] + bias[c0 + f*16 + lr];
      }
    }
    __syncthreads();
    const float* gsrc = (widx == 2) ? recv : send;
    float* gdst = (widx == 2) ? vrout : vsout;
#pragma unroll
    for (int k = 0; k < 4; ++k){
      int chunk = k*256 + tid;
      int r = chunk >> 4;
      int cc = (chunk & 15) * 4;
      int idx = (m0 + r)*256 + c0 + cc;
      f32x4 v = *(const f32x4*)&ldsF[r][cc];
      f32x4 g = *(const f32x4*)(gsrc + idx);
#pragma unroll
      for (int j = 0; j < 4; ++j) v[j] += g[j];
      *(f32x4*)(gdst + idx) = v;
    }
  }
}

// ---------------- K3b: pack vs per (b,h) into MFMA-B-frag-linear tiles ----------------
__global__ __launch_bounds__(256) void k_transV(const float* __restrict__ vsout,
                                                unsigned short* __restrict__ vpk){
  __shared__ float ldsT[32][129];
  int kv0 = blockIdx.x * 128;
  int bh = blockIdx.y;
  int b = bh >> 3, h = bh & 7;
  int tid = threadIdx.x;
#pragma unroll
  for (int p = 0; p < 4; ++p){
    int kvr = p*32 + (tid>>3);
    int dch = (tid&7)*4;
    f32x4 v = *(const f32x4*)(vsout + ((kv0 + kvr)*4 + b)*256 + h*32 + dch);
#pragma unroll
    for (int j = 0; j < 4; ++j) ldsT[dch+j][kvr] = v[j];
  }
  __syncthreads();
#pragma unroll
  for (int rep = 0; rep < 2; ++rep){
    int chunk = rep*256 + tid;
    int d   = chunk & 31;
    int sub = (chunk >> 5) & 3;
    int blk = chunk >> 7;            // 0..3
    int kvb = blk*32 + sub*8;        // local kv base
    ushort8 o;
#pragma unroll
    for (int j = 0; j < 8; ++j) o[j] = f2bf(ldsT[d][kvb + j]);
    *(ushort8*)(vpk + (bh*64 + (kv0>>5) + blk)*1024 + sub*256 + d*8) = o;
  }
}

// ---------------- K4: flash attention; 4 Q-frags per wave, kv-quarter split ----------------
// 1024 blocks: bh = (bid&7)+8*(bid>>8) (XCD-pinned), qt = (bid>>3)&31 (64 q each).
// Wave w = kv-quarter (512 kv, 8 tiles); each K/V fragment load feeds FOUR
// Q fragments (32 MFMA per 8 loads). m=0 => partials additive; 4-way LDS combine.
__global__ __launch_bounds__(256) void k_attn(const unsigned short* __restrict__ qbuf,
                                              const unsigned short* __restrict__ kpk,
                                              const unsigned short* __restrict__ vpk,
                                              const float* __restrict__ vrbuf,
                                              unsigned short* __restrict__ ctx){
  int bid = blockIdx.x;
  int bh  = (bid & 7) + ((bid >> 8) << 3);
  int qt0 = ((bid >> 3) & 31) * 64;
  int b = bh >> 3, h = bh & 7;
  int tid = threadIdx.x;
  int w = tid >> 6, lane = tid & 63;
  int lr = lane & 15, lg = lane >> 4;
  int lg4 = lg * 4;

  __shared__ float part[3][4][64][9];   // [wave-1][qfrag][lane][acc0 x4, acc1 x4, lsum]

  // Four Q fragments (pre-scaled by scale*log2e in k_proj)
  bf16x8 qf[4];
#pragma unroll
  for (int f = 0; f < 4; ++f)
    qf[f] = *(const bf16x8*)(qbuf + ((qt0 + f*16 + lr)*BATCH + b)*EMB + h*DHD + lg*8);

  // packed per-(b,h) fragment base pointers, offset to this wave's kv quarter
  const unsigned short* kbase = kpk + bh*65536 + w*16384 + lr*32 + lg*8;
  const unsigned short* vbase = vpk + bh*65536 + w*16384 + lg*256 + lr*8;

  f32x4 acc[4][2];
#pragma unroll
  for (int f = 0; f < 4; ++f){
    acc[f][0] = (f32x4){0.f,0.f,0.f,0.f};
    acc[f][1] = (f32x4){0.f,0.f,0.f,0.f};
  }
  float lsum[4] = {0.f, 0.f, 0.f, 0.f};

  bf16x8 kA[4], vA[4], kB[4], vB[4];

  auto loadfr = [&](int kv0, bf16x8* kf, bf16x8* vf){
#pragma unroll
    for (int j = 0; j < 4; ++j)
      kf[j] = *(const bf16x8*)(kbase + (kv0 + j*16)*32);
#pragma unroll
    for (int c = 0; c < 2; ++c)
#pragma unroll
      for (int dh = 0; dh < 2; ++dh)
        vf[c*2+dh] = *(const bf16x8*)(vbase + ((kv0>>5) + c)*1024 + dh*128);
  };

  auto tile_compute = [&](const bf16x8* kf, const bf16x8* vf){
    f32x4 z = (f32x4){0.f,0.f,0.f,0.f};
#pragma unroll
    for (int f = 0; f < 4; ++f){
      f32x4 s[4];
#pragma unroll
      for (int j = 0; j < 4; ++j)
        s[j] = __builtin_amdgcn_mfma_f32_16x16x32_bf16(kf[j], qf[f], z, 0, 0, 0);

      float p[4][4];
      float ps = 0.f;
#pragma unroll
      for (int j = 0; j < 4; ++j){
#pragma unroll
        for (int i = 0; i < 4; ++i){
          p[j][i] = fexp2(s[j][i]);
        }
        ps += (p[j][0] + p[j][1]) + (p[j][2] + p[j][3]);
      }
      lsum[f] += ps;

#pragma unroll
      for (int c = 0; c < 2; ++c){
        uint4v d;
        d[0] = __builtin_amdgcn_perm(__builtin_bit_cast(unsigned int, p[c][1]),
                                     __builtin_bit_cast(unsigned int, p[c][0]), 0x07060302u);
        d[1] = __builtin_amdgcn_perm(__builtin_bit_cast(unsigned int, p[c][3]),
                                     __builtin_bit_cast(unsigned int, p[c][2]), 0x07060302u);
        d[2] = __builtin_amdgcn_perm(__builtin_bit_cast(unsigned int, p[c+2][1]),
                                     __builtin_bit_cast(unsigned int, p[c+2][0]), 0x07060302u);
        d[3] = __builtin_amdgcn_perm(__builtin_bit_cast(unsigned int, p[c+2][3]),
                                     __builtin_bit_cast(unsigned int, p[c+2][2]), 0x07060302u);
        bf16x8 pf = __builtin_bit_cast(bf16x8, d);
        acc[f][0] = __builtin_amdgcn_mfma_f32_16x16x32_bf16(pf, vf[c*2+0], acc[f][0], 0, 0, 0);
        acc[f][1] = __builtin_amdgcn_mfma_f32_16x16x32_bf16(pf, vf[c*2+1], acc[f][1], 0, 0, 0);
      }
    }
  };

  loadfr(0, kA, vA);
  for (int t = 0; t < 8; t += 2){
    loadfr((t+1)*64, kB, vB);
    tile_compute(kA, vA);
    if (t + 2 < 8) loadfr((t+2)*64, kA, vA);
    tile_compute(kB, vB);
  }

  // reduce lsum across the 4 lane-groups (all lanes then hold partial row-sum for q=lr)
#pragma unroll
  for (int f = 0; f < 4; ++f){
    lsum[f] += __shfl_xor(lsum[f], 16);
    lsum[f] += __shfl_xor(lsum[f], 32);
  }

  // combine kv-quarters: waves 1-3 publish, wave 0 finalizes
  if (w > 0){
#pragma unroll
    for (int f = 0; f < 4; ++f){
#pragma unroll
      for (int i = 0; i < 4; ++i){
        part[w-1][f][lane][i]   = acc[f][0][i];
        part[w-1][f][lane][4+i] = acc[f][1][i];
      }
      part[w-1][f][lane][8] = lsum[f];
    }
  }
  __syncthreads();
  if (w == 0){
#pragma unroll
    for (int f = 0; f < 4; ++f){
#pragma unroll
      for (int ww = 0; ww < 3; ++ww){
#pragma unroll
        for (int i = 0; i < 4; ++i){
          acc[f][0][i] += part[ww][f][lane][i];
          acc[f][1][i] += part[ww][f][lane][4+i];
        }
        lsum[f] += part[ww][f][lane][8];
      }
      float inv = 1.0f / lsum[f];
#pragma unroll
      for (int i = 0; i < 4; ++i){
        float vinv = __shfl(inv, lg4 + i);    // 1/lsum for q = qt0+f*16+lg4+i
        int q = qt0 + f*16 + lg4 + i;
        int idx = (q*4 + b)*256 + h*DHD + lr;                 // row-major for vrbuf
        int pos = (q>>2)*4096 + h*512 + (4*(q&3)+b)*32 + lr;  // packed for ctx
        ctx[pos]      = f2bf(acc[f][0][i] * vinv + vrbuf[idx]);
        ctx[pos + 16] = f2bf(acc[f][1][i] * vinv + vrbuf[idx + 16]);
      }
    }
  }
}

// ---------------- K5: out = x + ctx @ Wo + bo (packed operands, staged epilogue) ----------------
__global__ __launch_bounds__(256) void k_out(const unsigned short* __restrict__ ctx,
                                             const unsigned short* __restrict__ wt,
                                             const float* __restrict__ bo,
                                             const float* __restrict__ x,
                                             float* __restrict__ out0){
  int m0 = blockIdx.x * 64;
  int c0 = blockIdx.y * 64;
  int tid = threadIdx.x;
  int w = tid >> 6, lane = tid & 63;
  int lr = lane & 15, lg = lane >> 4;

  __shared__ __align__(16) float ldsF[64][68];

  const unsigned short* apk = ctx + (m0/16 + w)*4096 + lr*32 + lg*8;
  const unsigned short* bpk = wt + 4*65536 + (c0/16)*4096 + lr*32 + lg*8;

  f32x4 acc[4];
#pragma unroll
  for (int f = 0; f < 4; ++f) acc[f] = (f32x4){0.f, 0.f, 0.f, 0.f};

#pragma unroll
  for (int k0 = 0; k0 < 256; k0 += 32){
    int kb = (k0 >> 5) * 512;
    bf16x8 af = *(const bf16x8*)(apk + kb);
#pragma unroll
    for (int f = 0; f < 4; ++f){
      bf16x8 bfrag = *(const bf16x8*)(bpk + f*4096 + kb);
      acc[f] = __builtin_amdgcn_mfma_f32_16x16x32_bf16(af, bfrag, acc[f], 0, 0, 0);
    }
  }

#pragma unroll
  for (int f = 0; f < 4; ++f){
#pragma unroll
    for (int i = 0; i < 4; ++i){
      ldsF[w*16 + lg*4 + i][f*16 + lr] = acc[f][i] + bo[c0 + f*16 + lr];
    }
  }
  __syncthreads();
#pragma unroll
  for (int k = 0; k < 4; ++k){
    int chunk = k*256 + tid;
    int r = chunk >> 4;
    int cc = (chunk & 15) * 4;
    int idx = (m0 + r)*256 + c0 + cc;
    f32x4 v = *(const f32x4*)&ldsF[r][cc];
    f32x4 g = *(const f32x4*)(x + idx);
#pragma unroll
    for (int j = 0; j < 4; ++j) v[j] += g[j];
    *(f32x4*)(out0 + idx) = v;
  }
}

extern "C" void kernel_launch(void* const* d_in, const int* in_sizes, int n_in,
                              void* d_out, int out_size, void* d_ws, size_t ws_size,
                              hipStream_t stream){
  const float* x    = (const float*)d_in[0];
  const float* qp   = (const float*)d_in[1];
  const float* recv = (const float*)d_in[2];
  const float* send = (const float*)d_in[3];
  const float* Wq   = (const float*)d_in[4];
  const float* bq   = (const float*)d_in[5];
  const float* Wk   = (const float*)d_in[6];
  const float* bk   = (const float*)d_in[7];
  const float* Wr   = (const float*)d_in[8];
  const float* br   = (const float*)d_in[9];
  const float* Wsv  = (const float*)d_in[10];
  const float* bsv  = (const float*)d_in[11];
  const float* Wo   = (const float*)d_in[12];
  const float* bo   = (const float*)d_in[13];

  float* out0  = (float*)d_out;
  float* vrout = out0 + NBE;
  float* vsout = out0 + 2*NBE;

  unsigned short* ws   = (unsigned short*)d_ws;
  unsigned short* qin  = ws;                 // packed; reused as packed ctx after proj
  unsigned short* qbuf = ws + NBE;
  unsigned short* kpk  = ws + 2*NBE;         // [32 bh][2048 kv perm][32 d]
  unsigned short* vpk  = ws + 3*NBE;         // [32 bh][64 tiles][1024] frag-linear
  unsigned short* wt   = ws + 4*NBE;         // 5 * 65536, packed

  hipLaunchKernelGGL(k_add, dim3(NBE/8/256), dim3(256), 0, stream, x, qp, qin);
  hipLaunchKernelGGL(k_transW, dim3(4, 4, 5), dim3(256), 0, stream, Wq, Wk, Wr, Wsv, Wo, wt);
  hipLaunchKernelGGL(k_proj, dim3(128, 16), dim3(256), 0, stream,
                     qin, wt, bq, bk, br, bsv, recv, send, qbuf, kpk, vrout, vsout);
  hipLaunchKernelGGL(k_transV, dim3(16, 32), dim3(256), 0, stream, vsout, vpk);
  hipLaunchKernelGGL(k_attn, dim3(1024), dim3(256), 0, stream,
                     qbuf, kpk, vpk, vrout, qin /*ctx, packed*/);
  hipLaunchKernelGGL(k_out, dim3(128, 4), dim3(256), 0, stream,
                     qin /*ctx*/, wt, bo, x, out0);
}

// Round 18
// 78.617 us; speedup vs baseline: 1.3321x; 1.0220x over previous
//
#include <hip/hip_runtime.h>
#include <hip/hip_bf16.h>

#define NTOK 2048
#define BATCH 4
#define EMB 256
#define NH 8
#define DHD 32
#define MROWS (NTOK*BATCH)      // 8192
#define NBE (MROWS*EMB)         // 2097152

typedef __attribute__((ext_vector_type(8))) __bf16 bf16x8;
typedef __attribute__((ext_vector_type(4))) float f32x4;
typedef __attribute__((ext_vector_type(8))) unsigned short ushort8;
typedef __attribute__((ext_vector_type(4))) unsigned int uint4v;

__device__ __forceinline__ unsigned short f2bf(float f){
  unsigned int u = __builtin_bit_cast(unsigned int, f);
  u += 0x7fffu + ((u >> 16) & 1u);
  return (unsigned short)(u >> 16);
}
__device__ __forceinline__ float fexp2(float x){
#if __has_builtin(__builtin_amdgcn_exp2f)
  return __builtin_amdgcn_exp2f(x);
#else
  return exp2f(x);
#endif
}

// fold 1/sqrt(32) * log2(e) into q so scores are in log2 domain
#define QSC (0.17677669529663687f * 1.4426950408889634f)

// Fragment-linear packing for [R][256] matrices:
//   pos(r,k) = (r>>4)*4096 + (k>>5)*512 + (r&15)*32 + (k&31)

// ---------------- K1: qpk = packed bf16(x + query_pos) ----------------
__global__ __launch_bounds__(256) void k_add(const float* __restrict__ x,
                                             const float* __restrict__ qp,
                                             unsigned short* __restrict__ qpk){
  int t = blockIdx.x * 256 + threadIdx.x;
  int ppos = t * 8;
  int tile = ppos >> 12;
  int rem  = ppos & 4095;
  int kc   = rem >> 9;
  int row  = (rem >> 5) & 15;
  int kk   = rem & 31;               // multiple of 8
  int src  = (tile*16 + row)*256 + kc*32 + kk;
  f32x4 a0 = *(const f32x4*)(x + src);
  f32x4 a1 = *(const f32x4*)(x + src + 4);
  f32x4 b0 = *(const f32x4*)(qp + src);
  f32x4 b1 = *(const f32x4*)(qp + src + 4);
  ushort8 o;
#pragma unroll
  for (int j = 0; j < 4; ++j){
    o[j]   = f2bf(a0[j] + b0[j]);
    o[j+4] = f2bf(a1[j] + b1[j]);
  }
  *(ushort8*)(qpk + ppos) = o;
}

// ---------------- K2: transpose+cast 5 weights into packed layout ----------------
__global__ __launch_bounds__(256) void k_transW(const float* __restrict__ s0,
                                                const float* __restrict__ s1,
                                                const float* __restrict__ s2,
                                                const float* __restrict__ s3,
                                                const float* __restrict__ s4,
                                                unsigned short* __restrict__ wt){
  const float* srcs[5] = {s0, s1, s2, s3, s4};
  __shared__ float lds[64][65];
  int wi = blockIdx.z;
  int k0 = blockIdx.x * 64;
  int n0 = blockIdx.y * 64;
  int tid = threadIdx.x;
  const float* src = srcs[wi];
#pragma unroll
  for (int p = 0; p < 4; ++p){
    int r = p*16 + (tid>>4);
    int c = (tid&15)*4;
    f32x4 v = *(const f32x4*)(src + (k0+r)*256 + n0 + c);
#pragma unroll
    for (int j = 0; j < 4; ++j) lds[r][c+j] = v[j];
  }
  __syncthreads();
#pragma unroll
  for (int p = 0; p < 4; ++p){
    int nr = p*16 + (tid>>4);
    int kc = (tid&15)*4;
    unsigned long long pk = 0;
#pragma unroll
    for (int j = 0; j < 4; ++j)
      pk |= ((unsigned long long)f2bf(lds[kc+j][nr])) << (16*j);
    int n_g = n0 + nr, k_g = k0 + kc;
    int pos = (n_g>>4)*4096 + (k_g>>5)*512 + (n_g&15)*32 + (k_g&31);
    *(unsigned long long*)(wt + wi*65536 + pos) = pk;
  }
}

// ---------------- K3: fused 4-way projection GEMM (packed operands) ----------------
// widx=3 (vs) epilogue additionally emits the vpk fragment-linear tiles
// (fuses the former k_transV kernel).
__global__ __launch_bounds__(256) void k_proj(const unsigned short* __restrict__ qpk,
                                              const unsigned short* __restrict__ wt,
                                              const float* __restrict__ bq,
                                              const float* __restrict__ bk,
                                              const float* __restrict__ br,
                                              const float* __restrict__ bs,
                                              const float* __restrict__ recv,
                                              const float* __restrict__ send,
                                              unsigned short* __restrict__ qbuf,
                                              unsigned short* __restrict__ kpk,
                                              unsigned short* __restrict__ vpk,
                                              float* __restrict__ vrout,
                                              float* __restrict__ vsout){
  int m0 = blockIdx.x * 64;
  int gc = blockIdx.y * 64;
  int widx = gc >> 8;
  int c0 = gc & 255;
  int tid = threadIdx.x;
  int w = tid >> 6, lane = tid & 63;
  int lr = lane & 15, lg = lane >> 4;

  __shared__ __align__(16) float shmemF[64*68];   // aliased: bf16 st view or f32 tile

  const unsigned short* apk = qpk + (m0/16 + w)*4096 + lr*32 + lg*8;
  const unsigned short* bpk = wt + widx*65536 + (c0/16)*4096 + lr*32 + lg*8;

  f32x4 acc[4];
#pragma unroll
  for (int f = 0; f < 4; ++f) acc[f] = (f32x4){0.f, 0.f, 0.f, 0.f};

#pragma unroll
  for (int k0 = 0; k0 < 256; k0 += 32){
    int kb = (k0 >> 5) * 512;
    bf16x8 af = *(const bf16x8*)(apk + kb);
#pragma unroll
    for (int f = 0; f < 4; ++f){
      bf16x8 bfrag = *(const bf16x8*)(bpk + f*4096 + kb);
      acc[f] = __builtin_amdgcn_mfma_f32_16x16x32_bf16(af, bfrag, acc[f], 0, 0, 0);
    }
  }

  const float* bias = (widx == 0) ? bq : (widx == 1) ? bk : (widx == 2) ? br : bs;

  if (widx <= 1){
    unsigned short (*st)[16][72] = (unsigned short(*)[16][72])shmemF;
#pragma unroll
    for (int f = 0; f < 4; ++f){
#pragma unroll
      for (int i = 0; i < 4; ++i){
        int c = c0 + f*16 + lr;
        float v = acc[f][i] + bias[c];
        st[w][lg*4+i][f*16+lr] = f2bf(widx == 0 ? v * QSC : v);
      }
    }
    if (widx == 0){
      int r = lane >> 2, co = (lane & 3) * 16;
      ushort8 a0 = *(ushort8*)&st[w][r][co];
      ushort8 a1 = *(ushort8*)&st[w][r][co + 8];
      unsigned short* dst = qbuf + (m0 + w*16 + r) * 256 + c0 + co;
      *(ushort8*)dst = a0;
      *(ushort8*)(dst + 8) = a1;
    } else {
      int cid = lane >> 3, s = lane & 7;
      int bb = cid >> 1, hr = cid & 1;
      int toko = s >> 1, dp = (s & 1) * 16;
      ushort8 a0 = *(ushort8*)&st[w][toko*4 + bb][hr*32 + dp];
      ushort8 a1 = *(ushort8*)&st[w][toko*4 + bb][hr*32 + dp + 8];
      int h  = (c0 >> 5) + hr;
      int n0 = (m0 + w*16) >> 2;
      int t0 = n0 & 63;
      int p0 = (((t0>>5)&1)<<4) + (((t0>>2)&1)<<5) + (((t0>>3)&3)<<2);
      unsigned short* dst = kpk + (bb*8 + h)*65536 + ((n0 & ~63) + p0 + toko)*32 + dp;
      *(ushort8*)dst = a0;
      *(ushort8*)(dst + 8) = a1;
    }
  } else {
    float (*ldsF)[68] = (float(*)[68])shmemF;
#pragma unroll
    for (int f = 0; f < 4; ++f){
#pragma unroll
      for (int i = 0; i < 4; ++i){
        ldsF[w*16 + lg*4 + i][f*16 + lr] = acc[f][i] + bias[c0 + f*16 + lr];
      }
    }
    __syncthreads();
    const float* gsrc = (widx == 2) ? recv : send;
    float* gdst = (widx == 2) ? vrout : vsout;
#pragma unroll
    for (int k = 0; k < 4; ++k){
      int chunk = k*256 + tid;
      int r = chunk >> 4;
      int cc = (chunk & 15) * 4;
      int idx = (m0 + r)*256 + c0 + cc;
      f32x4 v = *(const f32x4*)&ldsF[r][cc];
      f32x4 g = *(const f32x4*)(gsrc + idx);
#pragma unroll
      for (int j = 0; j < 4; ++j) v[j] += g[j];
      *(f32x4*)(gdst + idx) = v;
    }
    if (widx == 3){
      // fused transV: emit vpk tiles from the staged LDS block.
      // Block covers tokens n0t..n0t+15 (all 4 batches), heads {h0,h0+1}, d 0..31.
      // kv-local within 32-tile = (bid&1)*16 + s8*8 + j  =>  tile = bid>>1,
      // sub = 2*(bid&1)+s8, kv&7 = j.
      int bid = blockIdx.x;
      int tile = bid >> 1;
      int cid = tid >> 5;                 // 0..7 -> (b,hr)
      int bb = cid >> 1, hr = cid & 1;
      int d = tid & 31;
      int h0 = c0 >> 5;
      int bh = bb*8 + h0 + hr;
      unsigned short* tbase = vpk + (bh*64 + tile)*1024 + d*8;
#pragma unroll
      for (int s8 = 0; s8 < 2; ++s8){
        int sub = 2*(bid & 1) + s8;
        ushort8 o;
#pragma unroll
        for (int j = 0; j < 8; ++j)
          o[j] = f2bf(ldsF[(s8*8 + j)*4 + bb][hr*32 + d] + gsrc[(m0 + (s8*8+j)*4 + bb)*256 + c0 + hr*32 + d]);
        *(ushort8*)(tbase + sub*256) = o;
      }
    }
  }
}

// ---------------- K4: flash attention; 2 Q-frags per wave (r15 champion) ----------------
__global__ __launch_bounds__(256) void k_attn(const unsigned short* __restrict__ qbuf,
                                              const unsigned short* __restrict__ kpk,
                                              const unsigned short* __restrict__ vpk,
                                              const float* __restrict__ vrbuf,
                                              unsigned short* __restrict__ ctx){
  int bid = blockIdx.x;
  int bh  = (bid & 7) + ((bid >> 8) << 3);
  int qt0 = ((bid >> 3) & 31) * 64;
  int b = bh >> 3, h = bh & 7;
  int tid = threadIdx.x;
  int w = tid >> 6, lane = tid & 63;
  int wq = w & 1;        // q 32-group within block
  int wk = w >> 1;       // kv-half
  int lr = lane & 15, lg = lane >> 4;
  int lg4 = lg * 4;

  __shared__ float part[2][2][64][9];   // [wq][qfrag][lane][acc0 x4, acc1 x4, lsum]

  int qbase = qt0 + wq*32;
  bf16x8 qfA = *(const bf16x8*)(qbuf + ((qbase + lr)*BATCH + b)*EMB + h*DHD + lg*8);
  bf16x8 qfB = *(const bf16x8*)(qbuf + ((qbase + 16 + lr)*BATCH + b)*EMB + h*DHD + lg*8);

  const unsigned short* kbase = kpk + bh*65536 + wk*(1024*32) + lr*32 + lg*8;
  const unsigned short* vbase = vpk + bh*65536 + wk*(32*1024) + lg*256 + lr*8;

  f32x4 accA0 = (f32x4){0.f,0.f,0.f,0.f};
  f32x4 accA1 = (f32x4){0.f,0.f,0.f,0.f};
  f32x4 accB0 = (f32x4){0.f,0.f,0.f,0.f};
  f32x4 accB1 = (f32x4){0.f,0.f,0.f,0.f};
  float lsumA = 0.f, lsumB = 0.f;

  bf16x8 kA[4], vA[4], kB[4], vB[4];

  auto loadfr = [&](int kv0, bf16x8* kf, bf16x8* vf){
#pragma unroll
    for (int j = 0; j < 4; ++j)
      kf[j] = *(const bf16x8*)(kbase + (kv0 + j*16)*32);
#pragma unroll
    for (int c = 0; c < 2; ++c)
#pragma unroll
      for (int dh = 0; dh < 2; ++dh)
        vf[c*2+dh] = *(const bf16x8*)(vbase + ((kv0>>5) + c)*1024 + dh*128);
  };

  auto tile_compute = [&](const bf16x8* kf, const bf16x8* vf){
    f32x4 z = (f32x4){0.f,0.f,0.f,0.f};
    f32x4 sA[4], sB[4];
#pragma unroll
    for (int j = 0; j < 4; ++j){
      sA[j] = __builtin_amdgcn_mfma_f32_16x16x32_bf16(kf[j], qfA, z, 0, 0, 0);
      sB[j] = __builtin_amdgcn_mfma_f32_16x16x32_bf16(kf[j], qfB, z, 0, 0, 0);
    }

    float pA[4][4], pB[4][4];
    float psA = 0.f, psB = 0.f;
#pragma unroll
    for (int j = 0; j < 4; ++j){
#pragma unroll
      for (int i = 0; i < 4; ++i){
        pA[j][i] = fexp2(sA[j][i]);
        pB[j][i] = fexp2(sB[j][i]);
      }
      psA += (pA[j][0] + pA[j][1]) + (pA[j][2] + pA[j][3]);
      psB += (pB[j][0] + pB[j][1]) + (pB[j][2] + pB[j][3]);
    }
    lsumA += psA;
    lsumB += psB;

#pragma unroll
    for (int c = 0; c < 2; ++c){
      uint4v dA, dB;
      dA[0] = __builtin_amdgcn_perm(__builtin_bit_cast(unsigned int, pA[c][1]),
                                    __builtin_bit_cast(unsigned int, pA[c][0]), 0x07060302u);
      dA[1] = __builtin_amdgcn_perm(__builtin_bit_cast(unsigned int, pA[c][3]),
                                    __builtin_bit_cast(unsigned int, pA[c][2]), 0x07060302u);
      dA[2] = __builtin_amdgcn_perm(__builtin_bit_cast(unsigned int, pA[c+2][1]),
                                    __builtin_bit_cast(unsigned int, pA[c+2][0]), 0x07060302u);
      dA[3] = __builtin_amdgcn_perm(__builtin_bit_cast(unsigned int, pA[c+2][3]),
                                    __builtin_bit_cast(unsigned int, pA[c+2][2]), 0x07060302u);
      bf16x8 pfA = __builtin_bit_cast(bf16x8, dA);
      accA0 = __builtin_amdgcn_mfma_f32_16x16x32_bf16(pfA, vf[c*2+0], accA0, 0, 0, 0);
      accA1 = __builtin_amdgcn_mfma_f32_16x16x32_bf16(pfA, vf[c*2+1], accA1, 0, 0, 0);
      dB[0] = __builtin_amdgcn_perm(__builtin_bit_cast(unsigned int, pB[c][1]),
                                    __builtin_bit_cast(unsigned int, pB[c][0]), 0x07060302u);
      dB[1] = __builtin_amdgcn_perm(__builtin_bit_cast(unsigned int, pB[c][3]),
                                    __builtin_bit_cast(unsigned int, pB[c][2]), 0x07060302u);
      dB[2] = __builtin_amdgcn_perm(__builtin_bit_cast(unsigned int, pB[c+2][1]),
                                    __builtin_bit_cast(unsigned int, pB[c+2][0]), 0x07060302u);
      dB[3] = __builtin_amdgcn_perm(__builtin_bit_cast(unsigned int, pB[c+2][3]),
                                    __builtin_bit_cast(unsigned int, pB[c+2][2]), 0x07060302u);
      bf16x8 pfB = __builtin_bit_cast(bf16x8, dB);
      accB0 = __builtin_amdgcn_mfma_f32_16x16x32_bf16(pfB, vf[c*2+0], accB0, 0, 0, 0);
      accB1 = __builtin_amdgcn_mfma_f32_16x16x32_bf16(pfB, vf[c*2+1], accB1, 0, 0, 0);
    }
  };

  loadfr(0, kA, vA);
  for (int t = 0; t < 16; t += 2){
    loadfr((t+1)*64, kB, vB);
    tile_compute(kA, vA);
    if (t + 2 < 16) loadfr((t+2)*64, kA, vA);
    tile_compute(kB, vB);
  }

  lsumA += __shfl_xor(lsumA, 16);
  lsumA += __shfl_xor(lsumA, 32);
  lsumB += __shfl_xor(lsumB, 16);
  lsumB += __shfl_xor(lsumB, 32);

  if (wk == 1){
#pragma unroll
    for (int i = 0; i < 4; ++i){
      part[wq][0][lane][i]   = accA0[i];
      part[wq][0][lane][4+i] = accA1[i];
      part[wq][1][lane][i]   = accB0[i];
      part[wq][1][lane][4+i] = accB1[i];
    }
    part[wq][0][lane][8] = lsumA;
    part[wq][1][lane][8] = lsumB;
  }
  __syncthreads();
  if (wk == 0){
#pragma unroll
    for (int i = 0; i < 4; ++i){
      accA0[i] += part[wq][0][lane][i];
      accA1[i] += part[wq][0][lane][4+i];
      accB0[i] += part[wq][1][lane][i];
      accB1[i] += part[wq][1][lane][4+i];
    }
    lsumA += part[wq][0][lane][8];
    lsumB += part[wq][1][lane][8];
    float invA = 1.0f / lsumA;
    float invB = 1.0f / lsumB;
#pragma unroll
    for (int i = 0; i < 4; ++i){
      float vinvA = __shfl(invA, lg4 + i);
      float vinvB = __shfl(invB, lg4 + i);
      int qA = qbase + lg4 + i;
      int idxA = (qA*4 + b)*256 + h*DHD + lr;
      int posA = (qA>>2)*4096 + h*512 + (4*(qA&3)+b)*32 + lr;
      ctx[posA]      = f2bf(accA0[i] * vinvA + vrbuf[idxA]);
      ctx[posA + 16] = f2bf(accA1[i] * vinvA + vrbuf[idxA + 16]);
      int qB = qbase + 16 + lg4 + i;
      int idxB = (qB*4 + b)*256 + h*DHD + lr;
      int posB = (qB>>2)*4096 + h*512 + (4*(qB&3)+b)*32 + lr;
      ctx[posB]      = f2bf(accB0[i] * vinvB + vrbuf[idxB]);
      ctx[posB + 16] = f2bf(accB1[i] * vinvB + vrbuf[idxB + 16]);
    }
  }
}

// ---------------- K5: out = x + ctx @ Wo + bo (packed operands, staged epilogue) ----------------
__global__ __launch_bounds__(256) void k_out(const unsigned short* __restrict__ ctx,
                                             const unsigned short* __restrict__ wt,
                                             const float* __restrict__ bo,
                                             const float* __restrict__ x,
                                             float* __restrict__ out0){
  int m0 = blockIdx.x * 64;
  int c0 = blockIdx.y * 64;
  int tid = threadIdx.x;
  int w = tid >> 6, lane = tid & 63;
  int lr = lane & 15, lg = lane >> 4;

  __shared__ __align__(16) float ldsF[64][68];

  const unsigned short* apk = ctx + (m0/16 + w)*4096 + lr*32 + lg*8;
  const unsigned short* bpk = wt + 4*65536 + (c0/16)*4096 + lr*32 + lg*8;

  f32x4 acc[4];
#pragma unroll
  for (int f = 0; f < 4; ++f) acc[f] = (f32x4){0.f, 0.f, 0.f, 0.f};

#pragma unroll
  for (int k0 = 0; k0 < 256; k0 += 32){
    int kb = (k0 >> 5) * 512;
    bf16x8 af = *(const bf16x8*)(apk + kb);
#pragma unroll
    for (int f = 0; f < 4; ++f){
      bf16x8 bfrag = *(const bf16x8*)(bpk + f*4096 + kb);
      acc[f] = __builtin_amdgcn_mfma_f32_16x16x32_bf16(af, bfrag, acc[f], 0, 0, 0);
    }
  }

#pragma unroll
  for (int f = 0; f < 4; ++f){
#pragma unroll
    for (int i = 0; i < 4; ++i){
      ldsF[w*16 + lg*4 + i][f*16 + lr] = acc[f][i] + bo[c0 + f*16 + lr];
    }
  }
  __syncthreads();
#pragma unroll
  for (int k = 0; k < 4; ++k){
    int chunk = k*256 + tid;
    int r = chunk >> 4;
    int cc = (chunk & 15) * 4;
    int idx = (m0 + r)*256 + c0 + cc;
    f32x4 v = *(const f32x4*)&ldsF[r][cc];
    f32x4 g = *(const f32x4*)(x + idx);
#pragma unroll
    for (int j = 0; j < 4; ++j) v[j] += g[j];
    *(f32x4*)(out0 + idx) = v;
  }
}

extern "C" void kernel_launch(void* const* d_in, const int* in_sizes, int n_in,
                              void* d_out, int out_size, void* d_ws, size_t ws_size,
                              hipStream_t stream){
  const float* x    = (const float*)d_in[0];
  const float* qp   = (const float*)d_in[1];
  const float* recv = (const float*)d_in[2];
  const float* send = (const float*)d_in[3];
  const float* Wq   = (const float*)d_in[4];
  const float* bq   = (const float*)d_in[5];
  const float* Wk   = (const float*)d_in[6];
  const float* bk   = (const float*)d_in[7];
  const float* Wr   = (const float*)d_in[8];
  const float* br   = (const float*)d_in[9];
  const float* Wsv  = (const float*)d_in[10];
  const float* bsv  = (const float*)d_in[11];
  const float* Wo   = (const float*)d_in[12];
  const float* bo   = (const float*)d_in[13];

  float* out0  = (float*)d_out;
  float* vrout = out0 + NBE;
  float* vsout = out0 + 2*NBE;

  unsigned short* ws   = (unsigned short*)d_ws;
  unsigned short* qin  = ws;                 // packed; reused as packed ctx after proj
  unsigned short* qbuf = ws + NBE;
  unsigned short* kpk  = ws + 2*NBE;         // [32 bh][2048 kv perm][32 d]
  unsigned short* vpk  = ws + 3*NBE;         // [32 bh][64 tiles][1024] frag-linear
  unsigned short* wt   = ws + 4*NBE;         // 5 * 65536, packed

  hipLaunchKernelGGL(k_add, dim3(NBE/8/256), dim3(256), 0, stream, x, qp, qin);
  hipLaunchKernelGGL(k_transW, dim3(4, 4, 5), dim3(256), 0, stream, Wq, Wk, Wr, Wsv, Wo, wt);
  hipLaunchKernelGGL(k_proj, dim3(128, 16), dim3(256), 0, stream,
                     qin, wt, bq, bk, br, bsv, recv, send, qbuf, kpk, vpk, vrout, vsout);
  hipLaunchKernelGGL(k_attn, dim3(1024), dim3(256), 0, stream,
                     qbuf, kpk, vpk, vrout, qin /*ctx, packed*/);
  hipLaunchKernelGGL(k_out, dim3(128, 4), dim3(256), 0, stream,
                     qin /*ctx*/, wt, bo, x, out0);
}